// Round 9
// baseline (40.918 us; speedup 1.0000x reference)
//
#include <hip/hip_runtime.h>

// Problem constants (from reference):
//   codes:     [4096, 1376, 2] int32  (45 MB, read-once)
//   codebooks: [2, 256, 1, 8]  float32 (16 KB total, hot -> LDS)
//   scales:    [4096, 1, 1, 1] float32
//   out:       [4096, 11008]   float32 (180.4 MB, write-once)
//
// One float4 output per thread-iter (dense wave stores).
//   f = flat float4 index; pair = f>>1 selects codes; half = f&1 selects
//   which 16B half of the two 8-float codebook entries.
//
// Grid = 2048 blocks = exactly 8 blocks/CU resident (2048-thread cap) ->
// single occupancy wave, no tail quantization. 22 iters covers
// 2048*256*22 = 11,534,336 >= TOTAL_F4; last iter partially predicated.
#define NOG 4096
#define NIG 1376
#define BLOCK 256
#define NBLOCKS 2048
#define ITERS 22
#define TOTAL_F4 11272192                 // 4096*11008/4
#define ITER_STRIDE (NBLOCKS * BLOCK)     // 524,288 float4 per sweep

typedef float fx4 __attribute__((ext_vector_type(4)));
typedef int   ix2 __attribute__((ext_vector_type(2)));

__global__ __launch_bounds__(BLOCK)
void aqlm_dequant_kernel(const ix2* __restrict__ codes,      // [NOG*NIG]
                         const fx4* __restrict__ codebooks,  // 1024 fx4 (16 KB)
                         const float* __restrict__ scales,   // [NOG]
                         fx4* __restrict__ out)               // [TOTAL_F4]
{
    // Stage both codebooks in LDS once per block; amortized over 22 f4/thread.
    // book0 entry e -> lds_cb[2e, 2e+1]; book1 entry e -> lds_cb[512+2e, 512+2e+1]
    __shared__ fx4 lds_cb[1024];
    const int tid = threadIdx.x;
#pragma unroll
    for (int i = 0; i < 4; ++i)
        lds_cb[tid + i * BLOCK] = codebooks[tid + i * BLOCK];
    __syncthreads();

    const int base = blockIdx.x * BLOCK + tid;

#pragma unroll
    for (int it = 0; it < ITERS; ++it) {
        const int f = base + it * ITER_STRIDE;      // dense float4 index
        if (f < TOTAL_F4) {                         // only masks tail of iter 21
            const int pair = f >> 1;
            const int half = f & 1;
            const int og   = pair / NIG;            // magic-mul

            const ix2 c   = codes[pair];            // even/odd lanes share; 1 req
            const float s = scales[og];

            const fx4 a = lds_cb[c.x * 2 + half];
            const fx4 b = lds_cb[512 + c.y * 2 + half];

            out[f] = (a + b) * s;                   // dense, aligned 1 KB/wave
        }
    }
}

extern "C" void kernel_launch(void* const* d_in, const int* in_sizes, int n_in,
                              void* d_out, int out_size, void* d_ws, size_t ws_size,
                              hipStream_t stream) {
    const ix2*   codes     = (const ix2*)d_in[0];
    const fx4*   codebooks = (const fx4*)d_in[1];
    const float* scales    = (const float*)d_in[2];
    fx4*         out       = (fx4*)d_out;

    aqlm_dequant_kernel<<<NBLOCKS, BLOCK, 0, stream>>>(codes, codebooks, scales, out);
}

// Round 10
// 38.443 us; speedup vs baseline: 1.0644x; 1.0644x over previous
//
#include <hip/hip_runtime.h>

// Problem constants (from reference):
//   codes:     [4096, 1376, 2] int32  (45 MB, read-once)
//   codebooks: [2, 256, 1, 8]  float32 (16 KB total, hot -> LDS)
//   scales:    [4096, 1, 1, 1] float32
//   out:       [4096, 11008]   float32 (180.4 MB, write-once)
//
// Best measured config (Round 7: 38.16 us = 5.91 TB/s effective, 94% of the
// 6.3 TB/s D2D ceiling on 225.6 MB compulsory traffic).
//
// One float4 output per thread-iter (dense wave stores).
//   f = flat float4 index; pair = f>>1 selects codes; half = f&1 selects
//   which 16B half of the two 8-float codebook entries.
#define NOG 4096
#define NIG 1376
#define BLOCK 256
#define NBLOCKS 2752
#define ITERS 16
// float4 outputs total = 4096*11008/4 = 11,272,192 = 2752*256*16 exactly
#define ITER_STRIDE (NBLOCKS * BLOCK)   // 704,512 float4 per grid-iteration

typedef float fx4 __attribute__((ext_vector_type(4)));
typedef int   ix2 __attribute__((ext_vector_type(2)));

__global__ __launch_bounds__(BLOCK)
void aqlm_dequant_kernel(const ix2* __restrict__ codes,      // [NOG*NIG]
                         const fx4* __restrict__ codebooks,  // 1024 fx4 (16 KB)
                         const float* __restrict__ scales,   // [NOG]
                         fx4* __restrict__ out)               // [NOG*NIG*2]
{
    // Stage both codebooks in LDS once per block; amortized over 16 f4/thread.
    // book0 entry e -> lds_cb[2e, 2e+1]; book1 entry e -> lds_cb[512+2e, 512+2e+1]
    __shared__ fx4 lds_cb[1024];
    const int tid = threadIdx.x;
#pragma unroll
    for (int i = 0; i < 4; ++i)
        lds_cb[tid + i * BLOCK] = codebooks[tid + i * BLOCK];
    __syncthreads();

    const int base = blockIdx.x * BLOCK + tid;

#pragma unroll
    for (int it = 0; it < ITERS; ++it) {
        const int f    = base + it * ITER_STRIDE;   // dense float4 index
        const int pair = f >> 1;                    // (og, ig) pair index
        const int half = f & 1;                     // which 16B half of the 32B group
        const int og   = pair / NIG;                // magic-mul

        const ix2 c  = codes[pair];                 // even/odd lanes share an int2
        const float s = scales[og];

        const fx4 a = lds_cb[c.x * 2 + half];
        const fx4 b = lds_cb[512 + c.y * 2 + half];

        out[f] = (a + b) * s;   // wave store = contiguous, aligned 1 KB span
    }
}

extern "C" void kernel_launch(void* const* d_in, const int* in_sizes, int n_in,
                              void* d_out, int out_size, void* d_ws, size_t ws_size,
                              hipStream_t stream) {
    const ix2*   codes     = (const ix2*)d_in[0];
    const fx4*   codebooks = (const fx4*)d_in[1];
    const float* scales    = (const float*)d_in[2];
    fx4*         out       = (fx4*)d_out;

    aqlm_dequant_kernel<<<NBLOCKS, BLOCK, 0, stream>>>(codes, codebooks, scales, out);
}